// Round 8
// baseline (1212.090 us; speedup 1.0000x reference)
//
#include <hip/hip_runtime.h>
#include <hip/hip_bf16.h>
#include <math.h>

#define HD 128
#define KN 8
#define EM 10
#define MPB 8
#define EPB 2

typedef __attribute__((ext_vector_type(8))) short short8;
typedef __attribute__((ext_vector_type(4))) float f32x4;
typedef unsigned short ushort_t;
typedef unsigned int uint32;

#define MFMA(a, b, c) __builtin_amdgcn_mfma_f32_16x16x32_bf16(a, b, c, 0, 0, 0)

// ---- ws layout ----
#define WS_TE   0        // 16*128
#define WS_TM   2048     // 4*128
#define WS_AW2  2560     // 9*128
#define WS_EW2  3712     // 3*128
#define WS_CVEC 4096     // 128
#define FB_OFF 32768

__device__ __forceinline__ float bf2f(ushort_t u) {
  union { float f; uint32 i; } c; c.i = ((uint32)u) << 16; return c.f;
}
__device__ __forceinline__ ushort_t f2bf(float f) {
  union { float ff; uint32 u; } c; c.ff = f;
  uint32 r = c.u + 0x7fff + ((c.u >> 16) & 1);
  return (ushort_t)(r >> 16);
}
// byte offset in a 256B-row swizzled bf16 buffer
__device__ __forceinline__ int off256(int row, int by) {
  return row * 256 + (by ^ ((row & 7) << 4));
}

// ================= precompute: f32 tables =================
__global__ __launch_bounds__(128) void precompute_kernel(
    const float* __restrict__ type_emb, const float* __restrict__ atom_W,
    const float* __restrict__ atom_b, const float* __restrict__ edge_W,
    const float* __restrict__ edge_b, const float* __restrict__ motif_W,
    const float* __restrict__ me_W, const float* __restrict__ me_b,
    float n_nodes, float* __restrict__ ws)
{
  const int t = threadIdx.x;
  const int r = blockIdx.x;
  float acc = 0.0f;
  if (r < 16) {
    const int sc = r >> 2, ec = r & 3;
    for (int c = 0; c < HD; ++c)
      acc += (type_emb[sc*HD + c] + type_emb[ec*HD + c]) * me_W[c*HD + t];
    ws[WS_TE + r*HD + t] = acc;
  } else if (r < 20) {
    const int ty = r - 16;
    for (int c = 0; c < HD; ++c) {
      float tv = type_emb[ty*HD + c] * (c >= 64 ? n_nodes : 1.0f);
      acc += tv * motif_W[(HD + c)*HD + t];
    }
    ws[WS_TM + ty*HD + t] = acc;
  } else if (r < 29) {
    const int a = r - 20;
    for (int c = 0; c < HD; ++c)
      acc += atom_W[a*HD + c] * me_W[(HD + c)*HD + t];
    ws[WS_AW2 + a*HD + t] = acc;
  } else if (r < 32) {
    const int a = r - 29;
    for (int c = 0; c < HD; ++c)
      acc += edge_W[a*HD + c] * me_W[(HD + c)*HD + t];
    ws[WS_EW2 + a*HD + t] = acc;
  } else {
    acc = me_b[t];
    for (int c = 0; c < HD; ++c)
      acc += (6.0f*atom_b[c] + 8.0f*edge_b[c]) * me_W[(HD + c)*HD + t];
    ws[WS_CVEC + t] = acc;
  }
}

// ================= precompute: bf16 MFMA fragment buffer =================
// B-fragment layout for mfma_f32_16x16x32_bf16: lane l holds B[kt*32+8*(l>>4)+j][nt*16+(l&15)]
__global__ __launch_bounds__(64) void frag_kernel(
    const float* __restrict__ conv_W1, const float* __restrict__ conv_W2,
    const float* __restrict__ emlp_W, const float* __restrict__ motif_W,
    const float* __restrict__ atom_W, const float* __restrict__ edge_W,
    ushort_t* __restrict__ fbo)
{
  const int bid = blockIdx.x, l = threadIdx.x;
  int wi, kt, nt;
  if (bid < 256) { wi = bid >> 5; kt = (bid >> 3) & 3; nt = bid & 7; }
  else { int r = bid - 256; wi = 8 + (r >> 3); kt = 0; nt = r & 7; }
  const float* src; int Klim = 128;
  switch (wi) {
    case 0: src = conv_W1; break;
    case 1: src = conv_W2; break;
    case 2: src = conv_W1 + 16384; break;
    case 3: src = conv_W2 + 16384; break;
    case 4: src = emlp_W; break;
    case 5: src = emlp_W + 16384; break;
    case 6: src = emlp_W + 32768; break;
    case 7: src = motif_W; break;
    case 8: src = atom_W; Klim = 9; break;
    default: src = edge_W; Klim = 3; break;
  }
  size_t base = (wi < 8) ? (size_t)wi * 16384 : (size_t)131072 + (size_t)(wi - 8) * 4096;
  ushort_t* dst = fbo + base + ((size_t)(kt * 8 + nt) * 64 + l) * 8;
  #pragma unroll
  for (int j = 0; j < 8; ++j) {
    int k = kt * 32 + ((l >> 4) << 3) + j;
    int n = nt * 16 + (l & 15);
    float f = (k < Klim) ? src[k * HD + n] : 0.0f;
    dst[j] = f2bf(f);
  }
}

// ================= motif kernel =================
// r7 structure; this round targets the residual ~800 MB spill round-trip:
//  - emlp split into two single-accumulator passes (P2->Tb, then P1->Hb)
//  - B-fragment loads feed MFMAs directly (no bfr[8] staging arrays)
//  - conv layer loop kept rolled (#pragma unroll 1)
__global__ __launch_bounds__(256, 2) void motif_kernel(
    const float* __restrict__ x, const float* __restrict__ eag,
    const int* __restrict__ motif_nodes, const int* __restrict__ motif_types,
    const int* __restrict__ m_src, const int* __restrict__ m_dst,
    const int* __restrict__ m_eidx,
    const float* __restrict__ atom_b, const float* __restrict__ edge_b,
    const float* __restrict__ conv_b1, const float* __restrict__ conv_b2,
    const float* __restrict__ conv_eps,
    const float* __restrict__ attn_W, const float* __restrict__ attn_b,
    const float* __restrict__ emlp_b, const float* __restrict__ motif_b,
    const float* __restrict__ wsf, const ushort_t* __restrict__ fb,
    float* __restrict__ out)
{
  __shared__ __align__(16) char Hb[64 * 256];    // h / r / h_new / P1 (bf16, swizzled)
  __shared__ __align__(16) char Tb[64 * 256];    // xp+ep at init; z; P2
  __shared__ __align__(16) char EAb[80 * 256];   // ea / P3
  __shared__ __align__(16) char Cb[16 * 256];    // cat (rows 8..15 zero)
  __shared__ int nidx[64], sidx[80], didx[80], geidx[80], tty[8];
  __shared__ float qv[80], qsum[64], alph[64];
  __shared__ unsigned char zl[8][8][10];         // per-motif per-dst edge list (e | src<<4)
  __shared__ unsigned char zcnt[8][8];

  const int tid  = threadIdx.x;
  const int lane = tid & 63;
  const int wid  = tid >> 6;
  const int cl   = lane & 15;     // MFMA col / A-row-within-tile
  const int rg   = lane >> 4;     // MFMA k-group / D-row-group
  const int ch   = tid & 127;     // elementwise channel
  const int half = tid >> 7;
  const int m0   = blockIdx.x * MPB;

  // ---------- init ----------
  if (tid < 64) { nidx[tid] = motif_nodes[(size_t)m0 * 8 + tid]; qsum[tid] = 0.0f; }
  if (tid < 80) {
    sidx[tid]  = m_src [(size_t)m0 * 10 + tid];
    didx[tid]  = m_dst [(size_t)m0 * 10 + tid];
    geidx[tid] = m_eidx[(size_t)m0 * 10 + tid];
  }
  if (tid < 8) tty[tid] = motif_types[m0 + tid];
  { uint4 z4 = make_uint4(0, 0, 0, 0); *(uint4*)(Cb + tid * 16) = z4; }
  __syncthreads();

  // pad-stage xp [64][32] and ep [80][32] into Tb + build per-dst z-lists
  if (tid >= 192 && tid < 200) {
    int m = tid - 192;
    #pragma unroll
    for (int k = 0; k < 8; ++k) zcnt[m][k] = 0;
    for (int e = 0; e < 10; ++e) {
      int s = sidx[m * 10 + e];
      int d = didx[m * 10 + e];
      int c = zcnt[m][d];
      zl[m][d][c] = (unsigned char)(e | (s << 4));
      zcnt[m][d] = (unsigned char)(c + 1);
    }
  }
  for (int i = tid; i < 64 * 32; i += 256) {
    int row = i >> 5, k = i & 31;
    float f = (k < 9) ? x[(size_t)nidx[row] * 9 + k] : 0.0f;
    *(ushort_t*)(Tb + row * 64 + ((k * 2) ^ ((row & 3) << 4))) = f2bf(f);
  }
  for (int i = tid; i < 80 * 32; i += 256) {
    int row = i >> 5, k = i & 31;
    float f = (k < 3) ? eag[(size_t)geidx[row] * 3 + k] : 0.0f;
    *(ushort_t*)(Tb + 4096 + row * 64 + ((k * 2) ^ ((row & 3) << 4))) = f2bf(f);
  }
  __syncthreads();

  // ---------- h0 = xp @ atomW + atom_b ; ea = ep @ edgeW + edge_b ----------
  {
    const ushort_t* fbA = fb + 131072;           // wi8
    {
      int rb = wid * 16;
      int row = rb + cl;
      short8 a = *(const short8*)(Tb + row * 64 + ((rg << 4) ^ ((row & 3) << 4)));
      f32x4 acc[8];
      #pragma unroll
      for (int nt = 0; nt < 8; ++nt) { float bv = atom_b[nt * 16 + cl]; acc[nt] = f32x4{bv, bv, bv, bv}; }
      #pragma unroll
      for (int nt = 0; nt < 8; ++nt)
        acc[nt] = MFMA(a, *(const short8*)(fbA + ((size_t)nt * 64 + lane) * 8), acc[nt]);
      #pragma unroll
      for (int nt = 0; nt < 8; ++nt)
        #pragma unroll
        for (int i = 0; i < 4; ++i) {
          int row2 = rb + rg * 4 + i;
          *(ushort_t*)(Hb + off256(row2, (nt * 16 + cl) * 2)) = f2bf(acc[nt][i]);
        }
    }
    const ushort_t* fbE = fb + 131072 + 4096;    // wi9
    for (int mt = wid; mt < 5; mt += 4) {
      int rb = mt * 16;
      int row = rb + cl;
      short8 a = *(const short8*)(Tb + 4096 + row * 64 + ((rg << 4) ^ ((row & 3) << 4)));
      f32x4 acc[8];
      #pragma unroll
      for (int nt = 0; nt < 8; ++nt) { float bv = edge_b[nt * 16 + cl]; acc[nt] = f32x4{bv, bv, bv, bv}; }
      #pragma unroll
      for (int nt = 0; nt < 8; ++nt)
        acc[nt] = MFMA(a, *(const short8*)(fbE + ((size_t)nt * 64 + lane) * 8), acc[nt]);
      #pragma unroll
      for (int nt = 0; nt < 8; ++nt)
        #pragma unroll
        for (int i = 0; i < 4; ++i) {
          int row2 = rb + rg * 4 + i;
          *(ushort_t*)(EAb + off256(row2, (nt * 16 + cl) * 2)) = f2bf(acc[nt][i]);
        }
    }
  }
  __syncthreads();

  // ---------- conv layers ----------
  #pragma unroll 1
  for (int l = 0; l < 2; ++l) {
    const float epl = 1.0f + conv_eps[l];
    // z-phase: register gather, Hb -> Tb
    #pragma unroll
    for (int mi = 0; mi < 4; ++mi) {
      const int m = half * 4 + mi, r0 = m * 8, e0 = m * 10;
      float zk[8];
      #pragma unroll
      for (int k = 0; k < 8; ++k)
        zk[k] = epl * bf2f(*(const ushort_t*)(Hb + off256(r0 + k, ch * 2)));
      #pragma unroll
      for (int k = 0; k < 8; ++k) {
        const int cnt = zcnt[m][k];
        for (int j = 0; j < cnt; ++j) {
          const int p = zl[m][k][j];
          zk[k] += bf2f(*(const ushort_t*)(EAb + off256(e0 + (p & 15), ch * 2)))
                 * bf2f(*(const ushort_t*)(Hb  + off256(r0 + (p >> 4), ch * 2)));
        }
      }
      #pragma unroll
      for (int k = 0; k < 8; ++k)
        *(ushort_t*)(Tb + off256(r0 + k, ch * 2)) = f2bf(zk[k]);
    }
    __syncthreads();

    // GEMM1: r = relu(z @ W1 + b1) -> Hb
    {
      const ushort_t* fbW = fb + (size_t)(2 * l) * 16384;
      int rb = wid * 16;
      f32x4 acc[8];
      #pragma unroll
      for (int nt = 0; nt < 8; ++nt) { float bv = conv_b1[l * HD + nt * 16 + cl]; acc[nt] = f32x4{bv, bv, bv, bv}; }
      #pragma unroll
      for (int kt = 0; kt < 4; ++kt) {
        int row = rb + cl;
        short8 a = *(const short8*)(Tb + off256(row, kt * 64 + (rg << 4)));
        #pragma unroll
        for (int nt = 0; nt < 8; ++nt)
          acc[nt] = MFMA(a, *(const short8*)(fbW + ((size_t)(kt * 8 + nt) * 64 + lane) * 8), acc[nt]);
      }
      #pragma unroll
      for (int nt = 0; nt < 8; ++nt)
        #pragma unroll
        for (int i = 0; i < 4; ++i) {
          int row2 = rb + rg * 4 + i;
          *(ushort_t*)(Hb + off256(row2, (nt * 16 + cl) * 2)) = f2bf(fmaxf(acc[nt][i], 0.0f));
        }
    }
    // GEMM2: h = r @ W2 + b2 -> Hb (in-place, wave-local rows)
    {
      const ushort_t* fbW = fb + (size_t)(2 * l + 1) * 16384;
      int rb = wid * 16;
      int row = rb + cl;
      short8 a[4];
      #pragma unroll
      for (int kt = 0; kt < 4; ++kt)
        a[kt] = *(const short8*)(Hb + off256(row, kt * 64 + (rg << 4)));
      f32x4 acc[8];
      #pragma unroll
      for (int nt = 0; nt < 8; ++nt) { float bv = conv_b2[l * HD + nt * 16 + cl]; acc[nt] = f32x4{bv, bv, bv, bv}; }
      #pragma unroll
      for (int kt = 0; kt < 4; ++kt)
        #pragma unroll
        for (int nt = 0; nt < 8; ++nt)
          acc[nt] = MFMA(a[kt], *(const short8*)(fbW + ((size_t)(kt * 8 + nt) * 64 + lane) * 8), acc[nt]);
      #pragma unroll
      for (int nt = 0; nt < 8; ++nt)
        #pragma unroll
        for (int i = 0; i < 4; ++i) {
          int row2 = rb + rg * 4 + i;
          *(ushort_t*)(Hb + off256(row2, (nt * 16 + cl) * 2)) = f2bf(acc[nt][i]);
        }
    }
    __syncthreads();
  }

  // ---------- attention ----------
  {
    int j = tid & 3;
    for (int r = tid >> 2; r < 80; r += 64) {
      float p = 0.0f;
      #pragma unroll
      for (int i = 0; i < 32; ++i) {
        int c = i * 4 + j;
        p += bf2f(*(const ushort_t*)(EAb + off256(r, c * 2))) * attn_W[HD + c];
      }
      p += __shfl_xor(p, 1); p += __shfl_xor(p, 2);
      if (j == 0) qv[r] = p;
    }
  }
  __syncthreads();
  if (tid < 8) {
    int m = tid;
    #pragma unroll
    for (int e = 0; e < 10; ++e) {
      float q = qv[m * 10 + e];
      qsum[m * 8 + sidx[m * 10 + e]] += q;
      qsum[m * 8 + didx[m * 10 + e]] += q;
    }
  }
  __syncthreads();
  {
    int j = tid & 3, r = tid >> 2;
    float p = 0.0f;
    #pragma unroll
    for (int i = 0; i < 32; ++i) {
      int c = i * 4 + j;
      p += bf2f(*(const ushort_t*)(Hb + off256(r, c * 2))) * attn_W[c];
    }
    p += __shfl_xor(p, 1); p += __shfl_xor(p, 2);
    if (j == 0) alph[r] = 1.0f / (1.0f + __expf(-(p + qsum[r] + attn_b[0])));
  }
  __syncthreads();

  // h_nodes in regs
  float hn[4];
  #pragma unroll
  for (int mi = 0; mi < 4; ++mi) {
    int m = half * 4 + mi, r0 = m * 8;
    float s = 0.0f;
    #pragma unroll
    for (int k = 0; k < 8; ++k)
      s += alph[r0 + k] * bf2f(*(const ushort_t*)(Hb + off256(r0 + k, ch * 2)));
    hn[mi] = s;
  }
  __syncthreads();   // all reads of Hb done before P-passes overwrite

  // ---------- emlp pass 1: P2 = h @ WB -> Tb (Hb intact) ----------
  {
    const ushort_t* fbB = fb + (size_t)5 * 16384;
    int rb = wid * 16, row = rb + cl;
    f32x4 acc[8];
    #pragma unroll
    for (int nt = 0; nt < 8; ++nt) acc[nt] = f32x4{0, 0, 0, 0};
    #pragma unroll
    for (int kt = 0; kt < 4; ++kt) {
      short8 a = *(const short8*)(Hb + off256(row, kt * 64 + (rg << 4)));
      #pragma unroll
      for (int nt = 0; nt < 8; ++nt)
        acc[nt] = MFMA(a, *(const short8*)(fbB + ((size_t)(kt * 8 + nt) * 64 + lane) * 8), acc[nt]);
    }
    #pragma unroll
    for (int nt = 0; nt < 8; ++nt)
      #pragma unroll
      for (int i = 0; i < 4; ++i) {
        int row2 = rb + rg * 4 + i;
        *(ushort_t*)(Tb + off256(row2, (nt * 16 + cl) * 2)) = f2bf(acc[nt][i]);
      }
  }
  // ---------- emlp pass 2: P1 = h @ WA -> Hb (in-place, wave-local) ----------
  {
    const ushort_t* fbA = fb + (size_t)4 * 16384;
    int rb = wid * 16, row = rb + cl;
    short8 a[4];
    #pragma unroll
    for (int kt = 0; kt < 4; ++kt)
      a[kt] = *(const short8*)(Hb + off256(row, kt * 64 + (rg << 4)));
    f32x4 acc[8];
    #pragma unroll
    for (int nt = 0; nt < 8; ++nt) acc[nt] = f32x4{0, 0, 0, 0};
    #pragma unroll
    for (int kt = 0; kt < 4; ++kt)
      #pragma unroll
      for (int nt = 0; nt < 8; ++nt)
        acc[nt] = MFMA(a[kt], *(const short8*)(fbA + ((size_t)(kt * 8 + nt) * 64 + lane) * 8), acc[nt]);
    #pragma unroll
    for (int nt = 0; nt < 8; ++nt)
      #pragma unroll
      for (int i = 0; i < 4; ++i) {
        int row2 = rb + rg * 4 + i;
        *(ushort_t*)(Hb + off256(row2, (nt * 16 + cl) * 2)) = f2bf(acc[nt][i]);
      }
  }
  // ---------- emlp pass 3: P3 = ea @ WC -> EAb (in-place, wave-local tiles) ----------
  {
    const ushort_t* fbC = fb + (size_t)6 * 16384;
    for (int mt = wid; mt < 5; mt += 4) {
      int rb2 = mt * 16, row = rb2 + cl;
      short8 a[4];
      #pragma unroll
      for (int kt = 0; kt < 4; ++kt)
        a[kt] = *(const short8*)(EAb + off256(row, kt * 64 + (rg << 4)));
      f32x4 acc[8];
      #pragma unroll
      for (int nt = 0; nt < 8; ++nt) acc[nt] = f32x4{0, 0, 0, 0};
      #pragma unroll
      for (int kt = 0; kt < 4; ++kt)
        #pragma unroll
        for (int nt = 0; nt < 8; ++nt)
          acc[nt] = MFMA(a[kt], *(const short8*)(fbC + ((size_t)(kt * 8 + nt) * 64 + lane) * 8), acc[nt]);
      #pragma unroll
      for (int nt = 0; nt < 8; ++nt)
        #pragma unroll
        for (int i = 0; i < 4; ++i) {
          int row2 = rb2 + rg * 4 + i;
          *(ushort_t*)(EAb + off256(row2, (nt * 16 + cl) * 2)) = f2bf(acc[nt][i]);
        }
    }
  }
  __syncthreads();

  // ---------- h_edges + cat ----------
  {
    float eb = emlp_b[ch];
    #pragma unroll
    for (int mi = 0; mi < 4; ++mi) {
      int m = half * 4 + mi, r0 = m * 8;
      float he = 0.0f;
      #pragma unroll
      for (int e = 0; e < 10; ++e) {
        int s = sidx[m * 10 + e], d = didx[m * 10 + e];
        float v = bf2f(*(const ushort_t*)(Hb  + off256(r0 + s, ch * 2)))
                + bf2f(*(const ushort_t*)(Tb  + off256(r0 + d, ch * 2)))
                + bf2f(*(const ushort_t*)(EAb + off256(m * 10 + e, ch * 2))) + eb;
        he += fmaxf(v, 0.0f);
      }
      float cat = hn[mi] + 0.1f * he;
      *(ushort_t*)(Cb + off256(m, ch * 2)) = f2bf(cat);
    }
  }
  __syncthreads();

  // ---------- final: out = cat @ motifW_top + TM[type] + motif_b ----------
  {
    const ushort_t* fbM = fb + (size_t)7 * 16384;
    f32x4 acc[2];
    acc[0] = f32x4{0, 0, 0, 0}; acc[1] = f32x4{0, 0, 0, 0};
    #pragma unroll
    for (int kt = 0; kt < 4; ++kt) {
      int row = cl;
      short8 a = *(const short8*)(Cb + off256(row, kt * 64 + (rg << 4)));
      #pragma unroll
      for (int j = 0; j < 2; ++j) {
        int nt = wid * 2 + j;
        acc[j] = MFMA(a, *(const short8*)(fbM + ((size_t)(kt * 8 + nt) * 64 + lane) * 8), acc[j]);
      }
    }
    #pragma unroll
    for (int j = 0; j < 2; ++j)
      #pragma unroll
      for (int i = 0; i < 4; ++i) {
        int row = rg * 4 + i;
        if (row < 8) {
          int nt = wid * 2 + j, col = nt * 16 + cl;
          out[(size_t)(m0 + row) * HD + col] = acc[j][i] + motif_b[col] + wsf[WS_TM + tty[row] * HD + col];
        }
      }
  }
}

// ================= edge kernel =================
__global__ __launch_bounds__(256) void edge_kernel(
    const float* __restrict__ x, const float* __restrict__ eag,
    const int* __restrict__ motif_types, const int* __restrict__ mei,
    const int* __restrict__ attr_nodes, const int* __restrict__ attr_edges,
    const float* __restrict__ ws, float* __restrict__ out, int ME_)
{
  __shared__ int   ani[EPB][6];
  __shared__ int   aei[EPB][8];
  __shared__ float sxl[EPB][9];
  __shared__ float sel[EPB][3];
  __shared__ int   tei[EPB];

  const int tid = threadIdx.x;
  const int t = tid & (HD - 1);
  const int g = tid >> 7;
  const int me0 = blockIdx.x * EPB;

  if (tid < EPB*6) ani[tid/6][tid%6] = attr_nodes[(size_t)(me0 + tid/6)*6 + tid%6];
  if (tid >= 32 && tid < 32 + EPB*8) { int i = tid-32; aei[i/8][i%8] = attr_edges[(size_t)(me0 + i/8)*8 + i%8]; }
  if (tid >= 64 && tid < 64 + EPB) {
    const int e = tid - 64;
    const int a0 = mei[me0 + e], b0 = mei[ME_ + me0 + e];
    tei[e] = motif_types[a0]*4 + motif_types[b0];
  }
  __syncthreads();

  if (tid < EPB*9) {
    const int e = tid/9, a = tid%9;
    float s = 0.0f;
    #pragma unroll
    for (int p = 0; p < 6; ++p) s += x[(size_t)ani[e][p]*9 + a];
    sxl[e][a] = s;
  }
  if (tid >= 32 && tid < 32 + EPB*3) {
    const int i = tid-32, e = i/3, a = i%3;
    float s = 0.0f;
    #pragma unroll
    for (int p = 0; p < 8; ++p) s += eag[(size_t)aei[e][p]*3 + a];
    sel[e][a] = s;
  }
  __syncthreads();

  float acc = ws[WS_CVEC + t] + ws[WS_TE + tei[g]*HD + t];
  #pragma unroll
  for (int a = 0; a < 9; ++a) acc += sxl[g][a] * ws[WS_AW2 + a*HD + t];
  #pragma unroll
  for (int a = 0; a < 3; ++a) acc += sel[g][a] * ws[WS_EW2 + a*HD + t];
  out[(size_t)(me0 + g)*HD + t] = acc;
}

extern "C" void kernel_launch(void* const* d_in, const int* in_sizes, int n_in,
                              void* d_out, int out_size, void* d_ws, size_t ws_size,
                              hipStream_t stream) {
  const float* x          = (const float*)d_in[0];
  const float* eag        = (const float*)d_in[1];
  const int*   motif_nodes= (const int*)d_in[2];
  const int*   motif_types= (const int*)d_in[3];
  const int*   m_src      = (const int*)d_in[4];
  const int*   m_dst      = (const int*)d_in[5];
  const int*   m_eidx     = (const int*)d_in[6];
  const int*   mei        = (const int*)d_in[7];
  const int*   attr_nodes = (const int*)d_in[8];
  const int*   attr_edges = (const int*)d_in[9];
  const float* type_emb   = (const float*)d_in[10];
  const float* atom_W     = (const float*)d_in[11];
  const float* atom_b     = (const float*)d_in[12];
  const float* edge_W     = (const float*)d_in[13];
  const float* edge_b     = (const float*)d_in[14];
  const float* conv_W1    = (const float*)d_in[15];
  const float* conv_b1    = (const float*)d_in[16];
  const float* conv_W2    = (const float*)d_in[17];
  const float* conv_b2    = (const float*)d_in[18];
  const float* conv_eps   = (const float*)d_in[19];
  const float* attn_W     = (const float*)d_in[20];
  const float* attn_b     = (const float*)d_in[21];
  const float* emlp_W     = (const float*)d_in[22];
  const float* emlp_b     = (const float*)d_in[23];
  const float* motif_W    = (const float*)d_in[24];
  const float* motif_b    = (const float*)d_in[25];
  const float* me_W       = (const float*)d_in[26];
  const float* me_b       = (const float*)d_in[27];

  const int N_  = in_sizes[0] / 9;
  const int M_  = in_sizes[2] / 8;
  const int ME_ = in_sizes[7] / 2;

  float* wsf = (float*)d_ws;
  ushort_t* fb = (ushort_t*)((char*)d_ws + FB_OFF);
  float* out = (float*)d_out;

  precompute_kernel<<<33, 128, 0, stream>>>(type_emb, atom_W, atom_b, edge_W, edge_b,
                                            motif_W, me_W, me_b, (float)N_, wsf);
  frag_kernel<<<272, 64, 0, stream>>>(conv_W1, conv_W2, emlp_W, motif_W, atom_W, edge_W, fb);
  motif_kernel<<<M_/MPB, 256, 0, stream>>>(x, eag, motif_nodes, motif_types, m_src, m_dst, m_eidx,
      atom_b, edge_b, conv_b1, conv_b2, conv_eps, attn_W, attn_b, emlp_b, motif_b,
      wsf, fb, out);
  edge_kernel<<<ME_/EPB, 256, 0, stream>>>(x, eag, motif_types, mei, attr_nodes, attr_edges,
                                           wsf, out + (size_t)M_*HD, ME_);
}

// Round 9
// 645.330 us; speedup vs baseline: 1.8782x; 1.8782x over previous
//
#include <hip/hip_runtime.h>
#include <hip/hip_bf16.h>
#include <math.h>

#define HD 128
#define MPB 8
#define EPB 2

typedef __attribute__((ext_vector_type(8))) short short8;
typedef __attribute__((ext_vector_type(4))) float f32x4;
typedef unsigned short ushort_t;
typedef unsigned int uint32;

#define MFMA(a, b, c) __builtin_amdgcn_mfma_f32_16x16x32_bf16(a, b, c, 0, 0, 0)

// ---- ws layout ----
#define WS_TE   0        // 16*128
#define WS_TM   2048     // 4*128
#define WS_AW2  2560     // 9*128
#define WS_EW2  3712     // 3*128
#define WS_CVEC 4096     // 128
#define FB_OFF 32768

// fb byte offsets (each 128x128 bf16 weight = 32768 B, tile-major 32x1KB)
#define FB_W1(l)  ((size_t)(l) * 65536)
#define FB_W2(l)  ((size_t)(l) * 65536 + 32768)
#define FB_WA     131072
#define FB_WB     163840
#define FB_WC     196608
#define FB_WM     229376
#define FB_EMB    262144   // atom frags 8KB + edge frags 8KB, contiguous

__device__ __forceinline__ float bf2f(ushort_t u) {
  union { float f; uint32 i; } c; c.i = ((uint32)u) << 16; return c.f;
}
__device__ __forceinline__ ushort_t f2bf(float f) {
  union { float ff; uint32 u; } c; c.ff = f;
  uint32 r = c.u + 0x7fff + ((c.u >> 16) & 1);
  return (ushort_t)(r >> 16);
}
__device__ __forceinline__ int off256(int row, int by) {
  return row * 256 + (by ^ ((row & 7) << 4));
}

// cooperative 16KB global->LDS copy; bounded transient pressure (16 VGPRs)
__device__ __forceinline__ void stage16(char* __restrict__ Wb,
                                        const char* __restrict__ src, int tid) {
  uint4 t0 = *(const uint4*)(src + 0     + tid * 16);
  uint4 t1 = *(const uint4*)(src + 4096  + tid * 16);
  uint4 t2 = *(const uint4*)(src + 8192  + tid * 16);
  uint4 t3 = *(const uint4*)(src + 12288 + tid * 16);
  *(uint4*)(Wb + 0     + tid * 16) = t0;
  *(uint4*)(Wb + 4096  + tid * 16) = t1;
  *(uint4*)(Wb + 8192  + tid * 16) = t2;
  *(uint4*)(Wb + 12288 + tid * 16) = t3;
}

// ================= precompute: f32 tables =================
__global__ __launch_bounds__(128) void precompute_kernel(
    const float* __restrict__ type_emb, const float* __restrict__ atom_W,
    const float* __restrict__ atom_b, const float* __restrict__ edge_W,
    const float* __restrict__ edge_b, const float* __restrict__ motif_W,
    const float* __restrict__ me_W, const float* __restrict__ me_b,
    float n_nodes, float* __restrict__ ws)
{
  const int t = threadIdx.x;
  const int r = blockIdx.x;
  float acc = 0.0f;
  if (r < 16) {
    const int sc = r >> 2, ec = r & 3;
    for (int c = 0; c < HD; ++c)
      acc += (type_emb[sc*HD + c] + type_emb[ec*HD + c]) * me_W[c*HD + t];
    ws[WS_TE + r*HD + t] = acc;
  } else if (r < 20) {
    const int ty = r - 16;
    for (int c = 0; c < HD; ++c) {
      float tv = type_emb[ty*HD + c] * (c >= 64 ? n_nodes : 1.0f);
      acc += tv * motif_W[(HD + c)*HD + t];
    }
    ws[WS_TM + ty*HD + t] = acc;
  } else if (r < 29) {
    const int a = r - 20;
    for (int c = 0; c < HD; ++c)
      acc += atom_W[a*HD + c] * me_W[(HD + c)*HD + t];
    ws[WS_AW2 + a*HD + t] = acc;
  } else if (r < 32) {
    const int a = r - 29;
    for (int c = 0; c < HD; ++c)
      acc += edge_W[a*HD + c] * me_W[(HD + c)*HD + t];
    ws[WS_EW2 + a*HD + t] = acc;
  } else {
    acc = me_b[t];
    for (int c = 0; c < HD; ++c)
      acc += (6.0f*atom_b[c] + 8.0f*edge_b[c]) * me_W[(HD + c)*HD + t];
    ws[WS_CVEC + t] = acc;
  }
}

// ================= precompute: bf16 MFMA fragment buffer =================
__global__ __launch_bounds__(64) void frag_kernel(
    const float* __restrict__ conv_W1, const float* __restrict__ conv_W2,
    const float* __restrict__ emlp_W, const float* __restrict__ motif_W,
    const float* __restrict__ atom_W, const float* __restrict__ edge_W,
    ushort_t* __restrict__ fbo)
{
  const int bid = blockIdx.x, l = threadIdx.x;
  int wi, kt, nt;
  if (bid < 256) { wi = bid >> 5; kt = (bid >> 3) & 3; nt = bid & 7; }
  else { int r = bid - 256; wi = 8 + (r >> 3); kt = 0; nt = r & 7; }
  const float* src; int Klim = 128;
  switch (wi) {
    case 0: src = conv_W1; break;
    case 1: src = conv_W2; break;
    case 2: src = conv_W1 + 16384; break;
    case 3: src = conv_W2 + 16384; break;
    case 4: src = emlp_W; break;
    case 5: src = emlp_W + 16384; break;
    case 6: src = emlp_W + 32768; break;
    case 7: src = motif_W; break;
    case 8: src = atom_W; Klim = 9; break;
    default: src = edge_W; Klim = 3; break;
  }
  size_t base = (wi < 8) ? (size_t)wi * 16384 : (size_t)131072 + (size_t)(wi - 8) * 4096;
  ushort_t* dst = fbo + base + ((size_t)(kt * 8 + nt) * 64 + l) * 8;
  #pragma unroll
  for (int j = 0; j < 8; ++j) {
    int k = kt * 32 + ((l >> 4) << 3) + j;
    int n = nt * 16 + (l & 15);
    float f = (k < Klim) ? src[k * HD + n] : 0.0f;
    dst[j] = f2bf(f);
  }
}

// ================= motif kernel =================
// r8 structure + LDS-staged B-fragments: each weight staged into Wb (16KB) in
// two halves; GEMMs read B via ds_read_b128. Removes the per-wave in-flight
// global-load register pressure that caused the persistent spill (WRITE_SIZE
// 562-775 MB in r7/r8), and takes L2 latency off the MFMA critical path.
#define WTILE(t) (*(const short8*)(Wb + (((t) * 64 + lane) * 16)))

__global__ __launch_bounds__(256, 2) void motif_kernel(
    const float* __restrict__ x, const float* __restrict__ eag,
    const int* __restrict__ motif_nodes, const int* __restrict__ motif_types,
    const int* __restrict__ m_src, const int* __restrict__ m_dst,
    const int* __restrict__ m_eidx,
    const float* __restrict__ atom_b, const float* __restrict__ edge_b,
    const float* __restrict__ conv_b1, const float* __restrict__ conv_b2,
    const float* __restrict__ conv_eps,
    const float* __restrict__ attn_W, const float* __restrict__ attn_b,
    const float* __restrict__ emlp_b, const float* __restrict__ motif_b,
    const float* __restrict__ wsf, const ushort_t* __restrict__ fb,
    float* __restrict__ out)
{
  __shared__ __align__(16) char Hb[64 * 256];    // h / r / P1 (bf16, swizzled)
  __shared__ __align__(16) char Tb[64 * 256];    // xp+ep staging; z; P2
  __shared__ __align__(16) char EAb[80 * 256];   // ea / P3
  __shared__ __align__(16) char Cb[16 * 256];    // cat (rows 8..15 zero)
  __shared__ __align__(16) char Wb[16384];       // staged weight half
  __shared__ int nidx[64], sidx[80], didx[80], geidx[80], tty[8];
  __shared__ float qv[80], qsum[64], alph[64];
  __shared__ unsigned char zl[8][8][10];
  __shared__ unsigned char zcnt[8][8];

  const int tid  = threadIdx.x;
  const int lane = tid & 63;
  const int wid  = tid >> 6;
  const int cl   = lane & 15;
  const int rg   = lane >> 4;
  const int ch   = tid & 127;
  const int half = tid >> 7;
  const int m0   = blockIdx.x * MPB;
  const char* fbb = (const char*)fb;

  // ---------- init ----------
  if (tid < 64) { nidx[tid] = motif_nodes[(size_t)m0 * 8 + tid]; qsum[tid] = 0.0f; }
  if (tid < 80) {
    sidx[tid]  = m_src [(size_t)m0 * 10 + tid];
    didx[tid]  = m_dst [(size_t)m0 * 10 + tid];
    geidx[tid] = m_eidx[(size_t)m0 * 10 + tid];
  }
  if (tid < 8) tty[tid] = motif_types[m0 + tid];
  { uint4 z4 = make_uint4(0, 0, 0, 0); *(uint4*)(Cb + tid * 16) = z4; }
  __syncthreads();

  // ---------- stage xp/ep + embed weights + z-lists ----------
  stage16(Wb, fbb + FB_EMB, tid);
  if (tid >= 192 && tid < 200) {
    int m = tid - 192;
    #pragma unroll
    for (int k = 0; k < 8; ++k) zcnt[m][k] = 0;
    for (int e = 0; e < 10; ++e) {
      int s = sidx[m * 10 + e];
      int d = didx[m * 10 + e];
      int c = zcnt[m][d];
      zl[m][d][c] = (unsigned char)(e | (s << 4));
      zcnt[m][d] = (unsigned char)(c + 1);
    }
  }
  for (int i = tid; i < 64 * 32; i += 256) {
    int row = i >> 5, k = i & 31;
    float f = (k < 9) ? x[(size_t)nidx[row] * 9 + k] : 0.0f;
    *(ushort_t*)(Tb + row * 64 + ((k * 2) ^ ((row & 3) << 4))) = f2bf(f);
  }
  for (int i = tid; i < 80 * 32; i += 256) {
    int row = i >> 5, k = i & 31;
    float f = (k < 3) ? eag[(size_t)geidx[row] * 3 + k] : 0.0f;
    *(ushort_t*)(Tb + 4096 + row * 64 + ((k * 2) ^ ((row & 3) << 4))) = f2bf(f);
  }
  __syncthreads();

  // ---------- embed: h0 (Wb tiles 0-7), ea (Wb tiles 8-15) ----------
  {
    {
      int rb = wid * 16, row = rb + cl;
      short8 a = *(const short8*)(Tb + row * 64 + ((rg << 4) ^ ((row & 3) << 4)));
      f32x4 acc[8];
      #pragma unroll
      for (int nt = 0; nt < 8; ++nt) { float bv = atom_b[nt * 16 + cl]; acc[nt] = f32x4{bv, bv, bv, bv}; }
      #pragma unroll
      for (int nt = 0; nt < 8; ++nt) acc[nt] = MFMA(a, WTILE(nt), acc[nt]);
      #pragma unroll
      for (int nt = 0; nt < 8; ++nt)
        #pragma unroll
        for (int i = 0; i < 4; ++i)
          *(ushort_t*)(Hb + off256(rb + rg * 4 + i, (nt * 16 + cl) * 2)) = f2bf(acc[nt][i]);
    }
    for (int mt = wid; mt < 5; mt += 4) {
      int rb = mt * 16, row = rb + cl;
      short8 a = *(const short8*)(Tb + 4096 + row * 64 + ((rg << 4) ^ ((row & 3) << 4)));
      f32x4 acc[8];
      #pragma unroll
      for (int nt = 0; nt < 8; ++nt) { float bv = edge_b[nt * 16 + cl]; acc[nt] = f32x4{bv, bv, bv, bv}; }
      #pragma unroll
      for (int nt = 0; nt < 8; ++nt) acc[nt] = MFMA(a, WTILE(8 + nt), acc[nt]);
      #pragma unroll
      for (int nt = 0; nt < 8; ++nt)
        #pragma unroll
        for (int i = 0; i < 4; ++i)
          *(ushort_t*)(EAb + off256(rb + rg * 4 + i, (nt * 16 + cl) * 2)) = f2bf(acc[nt][i]);
    }
  }
  __syncthreads();

  // ---------- conv layers ----------
  #pragma unroll 1
  for (int l = 0; l < 2; ++l) {
    const float epl = 1.0f + conv_eps[l];
    // z-phase (Hb -> Tb) + stage W1 half0
    stage16(Wb, fbb + FB_W1(l), tid);
    #pragma unroll
    for (int mi = 0; mi < 4; ++mi) {
      const int m = half * 4 + mi, r0 = m * 8, e0 = m * 10;
      float zk[8];
      #pragma unroll
      for (int k = 0; k < 8; ++k)
        zk[k] = epl * bf2f(*(const ushort_t*)(Hb + off256(r0 + k, ch * 2)));
      #pragma unroll
      for (int k = 0; k < 8; ++k) {
        const int cnt = zcnt[m][k];
        for (int j = 0; j < cnt; ++j) {
          const int p = zl[m][k][j];
          zk[k] += bf2f(*(const ushort_t*)(EAb + off256(e0 + (p & 15), ch * 2)))
                 * bf2f(*(const ushort_t*)(Hb  + off256(r0 + (p >> 4), ch * 2)));
        }
      }
      #pragma unroll
      for (int k = 0; k < 8; ++k)
        *(ushort_t*)(Tb + off256(r0 + k, ch * 2)) = f2bf(zk[k]);
    }
    __syncthreads();

    // GEMM1: r = relu(z @ W1 + b1), Tb -> Hb
    {
      int rb = wid * 16, row = rb + cl;
      f32x4 acc[8];
      #pragma unroll
      for (int nt = 0; nt < 8; ++nt) { float bv = conv_b1[l * HD + nt * 16 + cl]; acc[nt] = f32x4{bv, bv, bv, bv}; }
      #pragma unroll
      for (int kt = 0; kt < 2; ++kt) {
        short8 a = *(const short8*)(Tb + off256(row, kt * 64 + (rg << 4)));
        #pragma unroll
        for (int nt = 0; nt < 8; ++nt) acc[nt] = MFMA(a, WTILE(kt * 8 + nt), acc[nt]);
      }
      __syncthreads();
      stage16(Wb, fbb + FB_W1(l) + 16384, tid);
      __syncthreads();
      #pragma unroll
      for (int kt = 2; kt < 4; ++kt) {
        short8 a = *(const short8*)(Tb + off256(row, kt * 64 + (rg << 4)));
        #pragma unroll
        for (int nt = 0; nt < 8; ++nt) acc[nt] = MFMA(a, WTILE((kt - 2) * 8 + nt), acc[nt]);
      }
      #pragma unroll
      for (int nt = 0; nt < 8; ++nt)
        #pragma unroll
        for (int i = 0; i < 4; ++i)
          *(ushort_t*)(Hb + off256(rb + rg * 4 + i, (nt * 16 + cl) * 2)) = f2bf(fmaxf(acc[nt][i], 0.0f));
    }
    __syncthreads();
    stage16(Wb, fbb + FB_W2(l), tid);
    __syncthreads();
    // GEMM2: h = r @ W2 + b2, Hb in-place (wave-local rows)
    {
      int rb = wid * 16, row = rb + cl;
      f32x4 acc[8];
      #pragma unroll
      for (int nt = 0; nt < 8; ++nt) { float bv = conv_b2[l * HD + nt * 16 + cl]; acc[nt] = f32x4{bv, bv, bv, bv}; }
      #pragma unroll
      for (int kt = 0; kt < 2; ++kt) {
        short8 a = *(const short8*)(Hb + off256(row, kt * 64 + (rg << 4)));
        #pragma unroll
        for (int nt = 0; nt < 8; ++nt) acc[nt] = MFMA(a, WTILE(kt * 8 + nt), acc[nt]);
      }
      __syncthreads();
      stage16(Wb, fbb + FB_W2(l) + 16384, tid);
      __syncthreads();
      #pragma unroll
      for (int kt = 2; kt < 4; ++kt) {
        short8 a = *(const short8*)(Hb + off256(row, kt * 64 + (rg << 4)));
        #pragma unroll
        for (int nt = 0; nt < 8; ++nt) acc[nt] = MFMA(a, WTILE((kt - 2) * 8 + nt), acc[nt]);
      }
      #pragma unroll
      for (int nt = 0; nt < 8; ++nt)
        #pragma unroll
        for (int i = 0; i < 4; ++i)
          *(ushort_t*)(Hb + off256(rb + rg * 4 + i, (nt * 16 + cl) * 2)) = f2bf(acc[nt][i]);
    }
    __syncthreads();
  }

  // ---------- attention ----------
  {
    int j = tid & 3;
    for (int r = tid >> 2; r < 80; r += 64) {
      float p = 0.0f;
      #pragma unroll
      for (int i = 0; i < 32; ++i) {
        int c = i * 4 + j;
        p += bf2f(*(const ushort_t*)(EAb + off256(r, c * 2))) * attn_W[HD + c];
      }
      p += __shfl_xor(p, 1); p += __shfl_xor(p, 2);
      if (j == 0) qv[r] = p;
    }
  }
  __syncthreads();
  if (tid < 8) {
    int m = tid;
    #pragma unroll
    for (int e = 0; e < 10; ++e) {
      float q = qv[m * 10 + e];
      qsum[m * 8 + sidx[m * 10 + e]] += q;
      qsum[m * 8 + didx[m * 10 + e]] += q;
    }
  }
  __syncthreads();
  {
    int j = tid & 3, r = tid >> 2;
    float p = 0.0f;
    #pragma unroll
    for (int i = 0; i < 32; ++i) {
      int c = i * 4 + j;
      p += bf2f(*(const ushort_t*)(Hb + off256(r, c * 2))) * attn_W[c];
    }
    p += __shfl_xor(p, 1); p += __shfl_xor(p, 2);
    if (j == 0) alph[r] = 1.0f / (1.0f + __expf(-(p + qsum[r] + attn_b[0])));
  }
  __syncthreads();

  // ---------- h_nodes in regs + stage WB half0 ----------
  stage16(Wb, fbb + FB_WB, tid);
  float hn[4];
  #pragma unroll
  for (int mi = 0; mi < 4; ++mi) {
    int m = half * 4 + mi, r0 = m * 8;
    float s = 0.0f;
    #pragma unroll
    for (int k = 0; k < 8; ++k)
      s += alph[r0 + k] * bf2f(*(const ushort_t*)(Hb + off256(r0 + k, ch * 2)));
    hn[mi] = s;
  }
  __syncthreads();

  // ---------- emlp pass 1: P2 = h @ WB -> Tb ----------
  {
    int rb = wid * 16, row = rb + cl;
    f32x4 acc[8];
    #pragma unroll
    for (int nt = 0; nt < 8; ++nt) acc[nt] = f32x4{0, 0, 0, 0};
    #pragma unroll
    for (int kt = 0; kt < 2; ++kt) {
      short8 a = *(const short8*)(Hb + off256(row, kt * 64 + (rg << 4)));
      #pragma unroll
      for (int nt = 0; nt < 8; ++nt) acc[nt] = MFMA(a, WTILE(kt * 8 + nt), acc[nt]);
    }
    __syncthreads();
    stage16(Wb, fbb + FB_WB + 16384, tid);
    __syncthreads();
    #pragma unroll
    for (int kt = 2; kt < 4; ++kt) {
      short8 a = *(const short8*)(Hb + off256(row, kt * 64 + (rg << 4)));
      #pragma unroll
      for (int nt = 0; nt < 8; ++nt) acc[nt] = MFMA(a, WTILE((kt - 2) * 8 + nt), acc[nt]);
    }
    #pragma unroll
    for (int nt = 0; nt < 8; ++nt)
      #pragma unroll
      for (int i = 0; i < 4; ++i)
        *(ushort_t*)(Tb + off256(rb + rg * 4 + i, (nt * 16 + cl) * 2)) = f2bf(acc[nt][i]);
  }
  __syncthreads();
  stage16(Wb, fbb + FB_WA, tid);
  __syncthreads();
  // ---------- emlp pass 2: P1 = h @ WA -> Hb in-place ----------
  {
    int rb = wid * 16, row = rb + cl;
    f32x4 acc[8];
    #pragma unroll
    for (int nt = 0; nt < 8; ++nt) acc[nt] = f32x4{0, 0, 0, 0};
    #pragma unroll
    for (int kt = 0; kt < 2; ++kt) {
      short8 a = *(const short8*)(Hb + off256(row, kt * 64 + (rg << 4)));
      #pragma unroll
      for (int nt = 0; nt < 8; ++nt) acc[nt] = MFMA(a, WTILE(kt * 8 + nt), acc[nt]);
    }
    __syncthreads();
    stage16(Wb, fbb + FB_WA + 16384, tid);
    __syncthreads();
    #pragma unroll
    for (int kt = 2; kt < 4; ++kt) {
      short8 a = *(const short8*)(Hb + off256(row, kt * 64 + (rg << 4)));
      #pragma unroll
      for (int nt = 0; nt < 8; ++nt) acc[nt] = MFMA(a, WTILE((kt - 2) * 8 + nt), acc[nt]);
    }
    #pragma unroll
    for (int nt = 0; nt < 8; ++nt)
      #pragma unroll
      for (int i = 0; i < 4; ++i)
        *(ushort_t*)(Hb + off256(rb + rg * 4 + i, (nt * 16 + cl) * 2)) = f2bf(acc[nt][i]);
  }
  __syncthreads();
  stage16(Wb, fbb + FB_WC, tid);
  __syncthreads();
  // ---------- emlp pass 3: P3 = ea @ WC -> EAb in-place (tiles wid, +4 for wave0) ----------
  {
    f32x4 pc[8], pc2[8];
    #pragma unroll
    for (int nt = 0; nt < 8; ++nt) { pc[nt] = f32x4{0, 0, 0, 0}; pc2[nt] = f32x4{0, 0, 0, 0}; }
    const int rowA = wid * 16 + cl;
    #pragma unroll
    for (int kt = 0; kt < 2; ++kt) {
      short8 a = *(const short8*)(EAb + off256(rowA, kt * 64 + (rg << 4)));
      #pragma unroll
      for (int nt = 0; nt < 8; ++nt) pc[nt] = MFMA(a, WTILE(kt * 8 + nt), pc[nt]);
    }
    if (wid == 0) {
      #pragma unroll
      for (int kt = 0; kt < 2; ++kt) {
        short8 a = *(const short8*)(EAb + off256(64 + cl, kt * 64 + (rg << 4)));
        #pragma unroll
        for (int nt = 0; nt < 8; ++nt) pc2[nt] = MFMA(a, WTILE(kt * 8 + nt), pc2[nt]);
      }
    }
    __syncthreads();
    stage16(Wb, fbb + FB_WC + 16384, tid);
    __syncthreads();
    #pragma unroll
    for (int kt = 2; kt < 4; ++kt) {
      short8 a = *(const short8*)(EAb + off256(rowA, kt * 64 + (rg << 4)));
      #pragma unroll
      for (int nt = 0; nt < 8; ++nt) pc[nt] = MFMA(a, WTILE((kt - 2) * 8 + nt), pc[nt]);
    }
    if (wid == 0) {
      #pragma unroll
      for (int kt = 2; kt < 4; ++kt) {
        short8 a = *(const short8*)(EAb + off256(64 + cl, kt * 64 + (rg << 4)));
        #pragma unroll
        for (int nt = 0; nt < 8; ++nt) pc2[nt] = MFMA(a, WTILE((kt - 2) * 8 + nt), pc2[nt]);
      }
    }
    #pragma unroll
    for (int nt = 0; nt < 8; ++nt)
      #pragma unroll
      for (int i = 0; i < 4; ++i)
        *(ushort_t*)(EAb + off256(wid * 16 + rg * 4 + i, (nt * 16 + cl) * 2)) = f2bf(pc[nt][i]);
    if (wid == 0) {
      #pragma unroll
      for (int nt = 0; nt < 8; ++nt)
        #pragma unroll
        for (int i = 0; i < 4; ++i)
          *(ushort_t*)(EAb + off256(64 + rg * 4 + i, (nt * 16 + cl) * 2)) = f2bf(pc2[nt][i]);
    }
  }
  __syncthreads();

  // ---------- h_edges + cat + stage WM half0 ----------
  stage16(Wb, fbb + FB_WM, tid);
  {
    float eb = emlp_b[ch];
    #pragma unroll
    for (int mi = 0; mi < 4; ++mi) {
      int m = half * 4 + mi, r0 = m * 8;
      float he = 0.0f;
      #pragma unroll
      for (int e = 0; e < 10; ++e) {
        int s = sidx[m * 10 + e], d = didx[m * 10 + e];
        float v = bf2f(*(const ushort_t*)(Hb  + off256(r0 + s, ch * 2)))
                + bf2f(*(const ushort_t*)(Tb  + off256(r0 + d, ch * 2)))
                + bf2f(*(const ushort_t*)(EAb + off256(m * 10 + e, ch * 2))) + eb;
        he += fmaxf(v, 0.0f);
      }
      float cat = hn[mi] + 0.1f * he;
      *(ushort_t*)(Cb + off256(m, ch * 2)) = f2bf(cat);
    }
  }
  __syncthreads();

  // ---------- final: out = cat @ motifW_top + TM[type] + motif_b ----------
  {
    f32x4 acc[2];
    acc[0] = f32x4{0, 0, 0, 0}; acc[1] = f32x4{0, 0, 0, 0};
    #pragma unroll
    for (int kt = 0; kt < 2; ++kt) {
      short8 a = *(const short8*)(Cb + off256(cl, kt * 64 + (rg << 4)));
      #pragma unroll
      for (int j = 0; j < 2; ++j)
        acc[j] = MFMA(a, WTILE(kt * 8 + wid * 2 + j), acc[j]);
    }
    __syncthreads();
    stage16(Wb, fbb + FB_WM + 16384, tid);
    __syncthreads();
    #pragma unroll
    for (int kt = 2; kt < 4; ++kt) {
      short8 a = *(const short8*)(Cb + off256(cl, kt * 64 + (rg << 4)));
      #pragma unroll
      for (int j = 0; j < 2; ++j)
        acc[j] = MFMA(a, WTILE((kt - 2) * 8 + wid * 2 + j), acc[j]);
    }
    #pragma unroll
    for (int j = 0; j < 2; ++j)
      #pragma unroll
      for (int i = 0; i < 4; ++i) {
        int row = rg * 4 + i;
        if (row < 8) {
          int nt = wid * 2 + j, col = nt * 16 + cl;
          out[(size_t)(m0 + row) * HD + col] = acc[j][i] + motif_b[col] + wsf[WS_TM + tty[row] * HD + col];
        }
      }
  }
}

// ================= edge kernel =================
__global__ __launch_bounds__(256) void edge_kernel(
    const float* __restrict__ x, const float* __restrict__ eag,
    const int* __restrict__ motif_types, const int* __restrict__ mei,
    const int* __restrict__ attr_nodes, const int* __restrict__ attr_edges,
    const float* __restrict__ ws, float* __restrict__ out, int ME_)
{
  __shared__ int   ani[EPB][6];
  __shared__ int   aei[EPB][8];
  __shared__ float sxl[EPB][9];
  __shared__ float sel[EPB][3];
  __shared__ int   tei[EPB];

  const int tid = threadIdx.x;
  const int t = tid & (HD - 1);
  const int g = tid >> 7;
  const int me0 = blockIdx.x * EPB;

  if (tid < EPB*6) ani[tid/6][tid%6] = attr_nodes[(size_t)(me0 + tid/6)*6 + tid%6];
  if (tid >= 32 && tid < 32 + EPB*8) { int i = tid-32; aei[i/8][i%8] = attr_edges[(size_t)(me0 + i/8)*8 + i%8]; }
  if (tid >= 64 && tid < 64 + EPB) {
    const int e = tid - 64;
    const int a0 = mei[me0 + e], b0 = mei[ME_ + me0 + e];
    tei[e] = motif_types[a0]*4 + motif_types[b0];
  }
  __syncthreads();

  if (tid < EPB*9) {
    const int e = tid/9, a = tid%9;
    float s = 0.0f;
    #pragma unroll
    for (int p = 0; p < 6; ++p) s += x[(size_t)ani[e][p]*9 + a];
    sxl[e][a] = s;
  }
  if (tid >= 32 && tid < 32 + EPB*3) {
    const int i = tid-32, e = i/3, a = i%3;
    float s = 0.0f;
    #pragma unroll
    for (int p = 0; p < 8; ++p) s += eag[(size_t)aei[e][p]*3 + a];
    sel[e][a] = s;
  }
  __syncthreads();

  float acc = ws[WS_CVEC + t] + ws[WS_TE + tei[g]*HD + t];
  #pragma unroll
  for (int a = 0; a < 9; ++a) acc += sxl[g][a] * ws[WS_AW2 + a*HD + t];
  #pragma unroll
  for (int a = 0; a < 3; ++a) acc += sel[g][a] * ws[WS_EW2 + a*HD + t];
  out[(size_t)(me0 + g)*HD + t] = acc;
}

extern "C" void kernel_launch(void* const* d_in, const int* in_sizes, int n_in,
                              void* d_out, int out_size, void* d_ws, size_t ws_size,
                              hipStream_t stream) {
  const float* x          = (const float*)d_in[0];
  const float* eag        = (const float*)d_in[1];
  const int*   motif_nodes= (const int*)d_in[2];
  const int*   motif_types= (const int*)d_in[3];
  const int*   m_src      = (const int*)d_in[4];
  const int*   m_dst      = (const int*)d_in[5];
  const int*   m_eidx     = (const int*)d_in[6];
  const int*   mei        = (const int*)d_in[7];
  const int*   attr_nodes = (const int*)d_in[8];
  const int*   attr_edges = (const int*)d_in[9];
  const float* type_emb   = (const float*)d_in[10];
  const float* atom_W     = (const float*)d_in[11];
  const float* atom_b     = (const float*)d_in[12];
  const float* edge_W     = (const float*)d_in[13];
  const float* edge_b     = (const float*)d_in[14];
  const float* conv_W1    = (const float*)d_in[15];
  const float* conv_b1    = (const float*)d_in[16];
  const float* conv_W2    = (const float*)d_in[17];
  const float* conv_b2    = (const float*)d_in[18];
  const float* conv_eps   = (const float*)d_in[19];
  const float* attn_W     = (const float*)d_in[20];
  const float* attn_b     = (const float*)d_in[21];
  const float* emlp_W     = (const float*)d_in[22];
  const float* emlp_b     = (const float*)d_in[23];
  const float* motif_W    = (const float*)d_in[24];
  const float* motif_b    = (const float*)d_in[25];
  const float* me_W       = (const float*)d_in[26];
  const float* me_b       = (const float*)d_in[27];

  const int N_  = in_sizes[0] / 9;
  const int M_  = in_sizes[2] / 8;
  const int ME_ = in_sizes[7] / 2;

  float* wsf = (float*)d_ws;
  ushort_t* fb = (ushort_t*)((char*)d_ws + FB_OFF);
  float* out = (float*)d_out;

  precompute_kernel<<<33, 128, 0, stream>>>(type_emb, atom_W, atom_b, edge_W, edge_b,
                                            motif_W, me_W, me_b, (float)N_, wsf);
  frag_kernel<<<272, 64, 0, stream>>>(conv_W1, conv_W2, emlp_W, motif_W, atom_W, edge_W, fb);
  motif_kernel<<<M_/MPB, 256, 0, stream>>>(x, eag, motif_nodes, motif_types, m_src, m_dst, m_eidx,
      atom_b, edge_b, conv_b1, conv_b2, conv_eps, attn_W, attn_b, emlp_b, motif_b,
      wsf, fb, out);
  edge_kernel<<<ME_/EPB, 256, 0, stream>>>(x, eag, motif_types, mei, attr_nodes, attr_edges,
                                           wsf, out + (size_t)M_*HD, ME_);
}